// Round 9
// baseline (434.566 us; speedup 1.0000x reference)
//
#include <hip/hip_runtime.h>

#define LOG2E 1.4426950408889634f
#define GRID 256
#define MAGIC_BOOT 100u

// fast sigmoid: rcp approx ~1e-6 rel; tolerance headroom is ~250x
__device__ __forceinline__ float fsig(float z) {
    return __builtin_amdgcn_rcpf(1.0f + exp2f(-z * LOG2E));
}

// ---------------------------------------------------------------------------
// Device-scope barrier v3: flat arrive (1 ACQ_REL RMW per block on a packed
// counter word), tree release (last arriver writes tag=101+slot to 8 group
// lines), waiters spin RELAXED on their group line then one ACQUIRE load.
// Monotone tags make release lines reusable: tag j+1 can only appear after
// every block passed slot j, so an equality spinner can never miss its tag.
// Layout: cnt[g*16] g=0..7 release lines; cnt[128+slot] packed arrive words.
// ---------------------------------------------------------------------------
template <int SLP>
__device__ __forceinline__ void grid_bar(unsigned* cnt, int slot) {
    __syncthreads();
    if (threadIdx.x == 0) {
        unsigned tag = 101u + (unsigned)slot;
        unsigned old = __hip_atomic_fetch_add(cnt + 128 + slot, 1u,
                                              __ATOMIC_ACQ_REL, __HIP_MEMORY_SCOPE_AGENT);
        if (old == GRID - 1u) {
            #pragma unroll
            for (int g = 0; g < 8; ++g)
                __hip_atomic_store(cnt + g * 16, tag,
                                   __ATOMIC_RELEASE, __HIP_MEMORY_SCOPE_AGENT);
        }
        unsigned* rel = cnt + (blockIdx.x & 7) * 16;
        while (__hip_atomic_load(rel, __ATOMIC_RELAXED, __HIP_MEMORY_SCOPE_AGENT) != tag)
            __builtin_amdgcn_s_sleep(SLP);
        (void)__hip_atomic_load(rel, __ATOMIC_ACQUIRE, __HIP_MEMORY_SCOPE_AGENT);
    }
    __syncthreads();
}

// ---------------------------------------------------------------------------
// conv3x3(roll(fb)*fade) + damping MLP at one pixel, fb in global (L2).
// ---------------------------------------------------------------------------
__device__ __forceinline__ void conv_damp(
    const float4* __restrict__ src, int yq, int xq, int ys, int xs,
    const float* fe, const float4 wr[9][4],
    const float4 d1w0, const float4 d1w1, const float2 d1b, const float4 d2p[4],
    float rv[4])
{
    float r[4] = { d2p[0].w, d2p[1].w, d2p[2].w, d2p[3].w };   // conv bias (fbb)
    #pragma unroll
    for (int a = 0; a < 3; ++a) {
        int yy = yq - 1 + a;
        float fy = fe[yy + 1];                       // 0 outside image -> zero pad
        const float4* rowp = src + (((yy - ys) & 63) << 6);
        #pragma unroll
        for (int qq = 0; qq < 3; ++qq) {
            int xt = xq - 1 + qq;
            float f = fy * fe[xt + 1];
            float4 v = rowp[(xt - xs) & 63];
            float s0 = v.x * f, s1 = v.y * f, s2 = v.z * f, s3 = v.w * f;
            #pragma unroll
            for (int co = 0; co < 4; ++co) {
                float4 w = wr[a * 3 + qq][co];
                r[co] = fmaf(w.x, s0, fmaf(w.y, s1, fmaf(w.z, s2, fmaf(w.w, s3, r[co]))));
            }
        }
    }
    float z0 = fmaf(d1w0.x, r[0], fmaf(d1w0.y, r[1], fmaf(d1w0.z, r[2], fmaf(d1w0.w, r[3], d1b.x))));
    float z1 = fmaf(d1w1.x, r[0], fmaf(d1w1.y, r[1], fmaf(d1w1.z, r[2], fmaf(d1w1.w, r[3], d1b.y))));
    float h0 = z0 * fsig(z0);
    float h1 = z1 * fsig(z1);
    #pragma unroll
    for (int c = 0; c < 4; ++c) {
        float dm = fsig(fmaf(d2p[c].x, h0, fmaf(d2p[c].y, h1, d2p[c].z)));
        rv[c] = r[c] * dm;
    }
}

// ---------------------------------------------------------------------------
// Single fused kernel: reverb (all 256 blocks, 1 row each) -> attention ->
// proj+blur -> final. 19 epoch barriers; boot tag replaces init launch.
// ---------------------------------------------------------------------------
__global__ __launch_bounds__(512) void fused_kernel(
    const float* __restrict__ x, const float* __restrict__ rw, const float* __restrict__ dl,
    const float* __restrict__ fbw, const float* __restrict__ fbb,
    const float* __restrict__ d1wg, const float* __restrict__ d1bg,
    const float* __restrict__ d2wg, const float* __restrict__ d2bg,
    const float* __restrict__ aiw, const float* __restrict__ aib,
    const float* __restrict__ aow, const float* __restrict__ aob,
    const float* __restrict__ swg, const float* __restrict__ sbg,
    const float* __restrict__ owg, const float* __restrict__ obg,
    float4* __restrict__ fbA, float4* __restrict__ fbB,
    float4* __restrict__ ws_wet, float* __restrict__ o_buf, float* __restrict__ blur_buf,
    unsigned* __restrict__ cnt, float* __restrict__ out)
{
    __shared__ float4 kvs4[2048];     // 32 KB: (k,v) pairs for 4096 keys
    __shared__ float2 part[2048];     // 16 KB: [kg][row_local]
    __shared__ float fe[66];
    __shared__ float4 wvsL[36];
    __shared__ float s_rw[16], s_dl[16];
    __shared__ float4 s_mlp[7];
    __shared__ float s_sw[288], s_ow[48], s_sb[8], s_ob[4];
    __shared__ float redmx[8], redmn[8];

    const int tid = threadIdx.x;
    const int blk = blockIdx.x;

    // ---- stage LDS statics (all blocks) ----
    if (tid < 66) {
        float f = 0.0f;
        if (tid >= 1 && tid <= 64) {
            int j = tid - 1;
            f = 1.0f;
            if (j < 4) f = 0.6f + (0.4f / 3.0f) * j;
            else if (j >= 60) f = 0.6f + (0.4f / 3.0f) * (63 - j);
        }
        fe[tid] = f;
    }
    if (tid >= 128 && tid < 164) {
        int t2 = tid - 128, n = t2 >> 2, co = t2 & 3;
        wvsL[t2] = make_float4(fbw[(co * 4 + 0) * 9 + n], fbw[(co * 4 + 1) * 9 + n],
                               fbw[(co * 4 + 2) * 9 + n], fbw[(co * 4 + 3) * 9 + n]);
    }
    if (tid >= 192 && tid < 208) s_rw[tid - 192] = rw[tid - 192];
    if (tid >= 224 && tid < 240) s_dl[tid - 224] = dl[tid - 224];
    if (tid == 256) {
        s_mlp[0] = make_float4(d1wg[0], d1wg[1], d1wg[2], d1wg[3]);
        s_mlp[1] = make_float4(d1wg[4], d1wg[5], d1wg[6], d1wg[7]);
        s_mlp[2] = make_float4(d1bg[0], d1bg[1], 0.0f, 0.0f);
        for (int c = 0; c < 4; ++c)
            s_mlp[3 + c] = make_float4(d2wg[c * 2], d2wg[c * 2 + 1], d2bg[c], fbb[c]);
    }
    if (tid >= 336 && tid < 384) s_ow[tid - 336] = owg[tid - 336];
    if (tid >= 384 && tid < 392) s_sb[tid - 384] = sbg[tid - 384];
    if (tid >= 392 && tid < 396) s_ob[tid - 392] = obg[tid - 392];
    for (int j = tid; j < 288; j += 512) s_sw[j] = swg[j];

    // ---- boot: block 0 zeros 19 arrive words, release-stores tag 100 to the
    // 8 group lines; others equality-spin (poison 0xAA.. can never match). ----
    if (blk == 0) {
        if (tid < 19) cnt[128 + tid] = 0u;
        __syncthreads();                       // zeroing + LDS statics done
        if (tid == 0) {
            #pragma unroll
            for (int g = 0; g < 8; ++g)
                __hip_atomic_store(cnt + g * 16, MAGIC_BOOT,
                                   __ATOMIC_RELEASE, __HIP_MEMORY_SCOPE_AGENT);
        }
    } else {
        __syncthreads();                       // LDS statics done
        if (tid == 0) {
            unsigned* rel = cnt + (blk & 7) * 16;
            while (__hip_atomic_load(rel, __ATOMIC_RELAXED, __HIP_MEMORY_SCOPE_AGENT) < MAGIC_BOOT ||
                   __hip_atomic_load(rel, __ATOMIC_RELAXED, __HIP_MEMORY_SCOPE_AGENT) > 200u)
                __builtin_amdgcn_s_sleep(2);
            (void)__hip_atomic_load(rel, __ATOMIC_ACQUIRE, __HIP_MEMORY_SCOPE_AGENT);
        }
        __syncthreads();
    }

    // =====================================================================
    // Stage 1: reverb, ALL 256 blocks. Block owns one image row (64 px),
    // wave 0 works 1 px/lane; other waves ride the barriers.
    // =====================================================================
    const int p   = (blk << 6) + (tid & 63);
    const int bb_ = p >> 12;
    const int s_  = p & 4095;
    const int y0  = s_ >> 6;
    const int xx  = s_ & 63;
    float4* A = fbA + (bb_ << 12);
    float4* B = fbB + (bb_ << 12);

    float4 wr[9][4];
    float4 d1w0, d1w1, d2p[4];
    float2 d1b;
    float4 fbv;
    float acc0 = 0.0f, acc1 = 0.0f, acc2 = 0.0f, acc3 = 0.0f;

    if (tid < 64) {
        #pragma unroll
        for (int n = 0; n < 9; ++n)
            #pragma unroll
            for (int co = 0; co < 4; ++co) wr[n][co] = wvsL[n * 4 + co];
        d1w0 = s_mlp[0]; d1w1 = s_mlp[1];
        d1b = make_float2(s_mlp[2].x, s_mlp[2].y);
        d2p[0] = s_mlp[3]; d2p[1] = s_mlp[4]; d2p[2] = s_mlp[5]; d2p[3] = s_mlp[6];

        fbv.x = 0.1f * x[((bb_ * 4 + 0) << 12) + s_];
        fbv.y = 0.1f * x[((bb_ * 4 + 1) << 12) + s_];
        fbv.z = 0.1f * x[((bb_ * 4 + 2) << 12) + s_];
        fbv.w = 0.1f * x[((bb_ * 4 + 3) << 12) + s_];
        A[s_] = fbv;
    }
    grid_bar<1>(cnt, 0);

    float decay = 1.0f;
    for (int i = 0; i < 16; ++i) {
        if (tid < 64) {
            const float4* src = (i & 1) ? B : A;
            float4* dst = (i & 1) ? A : B;
            float d = s_dl[i];
            int ys  = ((int)(3.0f * d)) & 63;
            int xs  = ((int)(6.0f * d)) & 63;
            int ys2 = ((int)(1.5f * d)) & 63;
            int xs2 = ((int)(3.0f * d)) & 63;
            float wgt = fsig(s_rw[i]) * decay * 3.0f;

            float rv[4];
            conv_damp(src, y0, xx, ys, xs, fe, wr, d1w0, d1w1, d1b, d2p, rv);
            acc0 = fmaf(rv[0], wgt, acc0);
            acc1 = fmaf(rv[1], wgt, acc1);
            acc2 = fmaf(rv[2], wgt, acc2);
            acc3 = fmaf(rv[3], wgt, acc3);
            float4 fnew = make_float4(fbv.x + 0.24f * rv[0], fbv.y + 0.24f * rv[1],
                                      fbv.z + 0.24f * rv[2], fbv.w + 0.24f * rv[3]);
            if (i > 0) {
                int yr = (y0 - ys2) & 63, xr = (xx - xs2) & 63;
                float rvr[4];
                conv_damp(src, yr, xr, ys, xs, fe, wr, d1w0, d1w1, d1b, d2p, rvr);
                float4 fr = src[(yr << 6) + xr];
                float f = 0.08f * fe[y0 + 1] * fe[xx + 1];
                fnew.x = fmaf(f, fmaf(0.24f, rvr[0], fr.x), fnew.x);
                fnew.y = fmaf(f, fmaf(0.24f, rvr[1], fr.y), fnew.y);
                fnew.z = fmaf(f, fmaf(0.24f, rvr[2], fr.z), fnew.z);
                fnew.w = fmaf(f, fmaf(0.24f, rvr[3], fr.w), fnew.w);
            }
            dst[s_] = fnew;
            fbv = fnew;
        }
        decay *= 0.8f;
        if (i < 15) grid_bar<1>(cnt, 1 + i);
    }
    if (tid < 64) ws_wet[p] = make_float4(acc0, acc1, acc2, acc3);
    grid_bar<1>(cnt, 16);

    // =====================================================================
    // Stage 2: attention (head_dim=1). Block = (b,h, 256-row chunk).
    // 512 thr = 64 row-slots (4 rows each) x 8 key-groups (512 keys each).
    // =====================================================================
    {
        const int bh = blk >> 4;
        const int ab = bh >> 2, ah = bh & 3;
        const int qc = blk & 15;

        float wq[4], wk[4], wv[4];
        #pragma unroll
        for (int c = 0; c < 4; ++c) {
            wq[c] = aiw[ah * 4 + c];
            wk[c] = aiw[(4 + ah) * 4 + c];
            wv[c] = aiw[(8 + ah) * 4 + c];
        }
        const float bq = aib[ah], bk = aib[4 + ah], bv = aib[8 + ah];

        float2* kvs = (float2*)kvs4;
        float lmax = -1e30f, lmin = 1e30f;
        for (int s = tid; s < 4096; s += 512) {
            float4 w4 = ws_wet[(ab << 12) + s];
            float k = wk[0] * w4.x + wk[1] * w4.y + wk[2] * w4.z + wk[3] * w4.w + bk;
            float v = wv[0] * w4.x + wv[1] * w4.y + wv[2] * w4.z + wv[3] * w4.w + bv;
            kvs[s] = make_float2(k, v);
            lmax = fmaxf(lmax, k); lmin = fminf(lmin, k);
        }
        #pragma unroll
        for (int off = 32; off > 0; off >>= 1) {
            lmax = fmaxf(lmax, __shfl_xor(lmax, off));
            lmin = fminf(lmin, __shfl_xor(lmin, off));
        }
        if ((tid & 63) == 0) { redmx[tid >> 6] = lmax; redmn[tid >> 6] = lmin; }
        __syncthreads();
        float kmax = redmx[0], kmin = redmn[0];
        #pragma unroll
        for (int w = 1; w < 8; ++w) { kmax = fmaxf(kmax, redmx[w]); kmin = fminf(kmin, redmn[w]); }

        const int rs = tid & 63;
        const int kg = tid >> 6;
        float qL[4], mL[4];
        #pragma unroll
        for (int rr = 0; rr < 4; ++rr) {
            int row = (qc << 8) + (rs << 2) + rr;
            float4 w4 = ws_wet[(ab << 12) + row];
            float q = wq[0] * w4.x + wq[1] * w4.y + wq[2] * w4.z + wq[3] * w4.w + bq;
            float m = (q >= 0.0f) ? q * kmax : q * kmin;   // exact row max (hd=1)
            qL[rr] = q * LOG2E; mL[rr] = m * LOG2E;
        }

        float den[4] = {0, 0, 0, 0}, num[4] = {0, 0, 0, 0};
        const int j0 = kg << 8;        // 256 float4 = 512 keys per group
        #pragma unroll 2
        for (int j = j0; j < j0 + 256; ++j) {
            float4 t = kvs4[j];
            #pragma unroll
            for (int rr = 0; rr < 4; ++rr) {
                float e0 = exp2f(fmaf(qL[rr], t.x, -mL[rr]));
                float e1 = exp2f(fmaf(qL[rr], t.z, -mL[rr]));
                den[rr] += e0 + e1;
                num[rr] = fmaf(e0, t.y, fmaf(e1, t.w, num[rr]));
            }
        }
        #pragma unroll
        for (int rr = 0; rr < 4; ++rr)
            part[(kg << 8) + (rs << 2) + rr] = make_float2(den[rr], num[rr]);
        __syncthreads();
        if (tid < 256) {
            float dd = 0.0f, nn = 0.0f;
            #pragma unroll
            for (int g = 0; g < 8; ++g) {
                float2 pp = part[(g << 8) + tid];
                dd += pp.x; nn += pp.y;
            }
            int row = (qc << 8) + tid;
            o_buf[(((ab << 12) + row) << 2) + ah] = nn * __builtin_amdgcn_rcpf(dd);
        }
    }
    grid_bar<2>(cnt, 17);

    // =====================================================================
    // Stage 3: attn out-projection + 3x3 box blur (on the fly, zero pad).
    // Block = (plane bc, 4-row slab). Threads 0..255: 1 px each.
    // =====================================================================
    {
        const int bc = blk >> 4;
        const int sub = blk & 15;
        const int pb = bc >> 2, pc = bc & 3;
        const float w0 = aow[pc * 4], w1 = aow[pc * 4 + 1],
                    w2 = aow[pc * 4 + 2], w3 = aow[pc * 4 + 3];
        const float bbp = aob[pc];
        if (tid < 256) {
            int yq = (sub << 2) + (tid >> 6);
            int xq = tid & 63;
            float acc = 0.0f;
            for (int dy = -1; dy <= 1; ++dy) {
                int yy = yq + dy; if (yy < 0 || yy > 63) continue;
                for (int dx = -1; dx <= 1; ++dx) {
                    int xc = xq + dx; if (xc < 0 || xc > 63) continue;
                    float4 o4 = ((const float4*)o_buf)[(pb << 12) + (yy << 6) + xc];
                    acc += w0 * o4.x + w1 * o4.y + w2 * o4.z + w3 * o4.w + bbp;
                }
            }
            blur_buf[(bc << 12) + (yq << 6) + xq] = acc * (1.0f / 9.0f);
        }
    }
    grid_bar<2>(cnt, 18);

    // =====================================================================
    // Stage 4: edge enhance + spatial conv + 1x1 combine + dry/wet mix.
    // Block owns 64 px; thread = (px 0..63, cout 0..3); tid<256 active.
    // =====================================================================
    if (tid < 256) {
        const int co = tid >> 6;
        const int pl = (blk << 6) + (tid & 63);
        const int fb_ = pl >> 12, ss = pl & 4095;
        const int y = ss >> 6, xx0 = ss & 63;

        float spat[8];
        #pragma unroll
        for (int j = 0; j < 8; ++j) spat[j] = s_sb[j];
        for (int dy = -1; dy <= 1; ++dy) {
            int yy = y + dy;
            if (yy < 0 || yy > 63) continue;
            for (int dx = -1; dx <= 1; ++dx) {
                int xc = xx0 + dx;
                if (xc < 0 || xc > 63) continue;
                int ky = dy + 1, kx = dx + 1;
                #pragma unroll
                for (int ci = 0; ci < 4; ++ci) {
                    float xv = x[((fb_ * 4 + ci) << 12) + (yy << 6) + xc];
                    #pragma unroll
                    for (int j = 0; j < 8; ++j)
                        spat[j] += s_sw[((j * 4 + ci) * 3 + ky) * 3 + kx] * xv;
                }
            }
        }
        float wetF[4];
        #pragma unroll
        for (int c = 0; c < 4; ++c) {
            const float* plb = blur_buf + ((fb_ * 4 + c) << 12);
            float center = plb[ss];
            float sum9 = 0.0f;
            for (int dy = -1; dy <= 1; ++dy) {
                int yy = y + dy;
                if (yy < 0 || yy > 63) continue;
                for (int dx = -1; dx <= 1; ++dx) {
                    int xc = xx0 + dx;
                    if (xc < 0 || xc > 63) continue;
                    sum9 += plb[(yy << 6) + xc];
                }
            }
            wetF[c] = center + 0.04f * (9.0f * center - sum9);
        }
        float pv = s_ob[co];
        #pragma unroll
        for (int j = 0; j < 8; ++j) pv += s_ow[co * 12 + j] * spat[j];
        #pragma unroll
        for (int c = 0; c < 4; ++c) pv += s_ow[co * 12 + 8 + c] * wetF[c];
        float xc0 = x[((fb_ * 4 + co) << 12) + ss];
        out[((fb_ * 4 + co) << 12) + ss] = 0.7f * xc0 + 0.3f * pv;
    }
}

// ---------------------------------------------------------------------------
extern "C" void kernel_launch(void* const* d_in, const int* in_sizes, int n_in,
                              void* d_out, int out_size, void* d_ws, size_t ws_size,
                              hipStream_t stream)
{
    (void)in_sizes; (void)n_in; (void)out_size; (void)ws_size;
    const float* x    = (const float*)d_in[0];
    const float* rw   = (const float*)d_in[1];
    const float* dl   = (const float*)d_in[2];
    // d_in[3] diffusion_strength: unused by reference
    const float* sw   = (const float*)d_in[4];
    const float* sb   = (const float*)d_in[5];
    const float* fbw  = (const float*)d_in[6];
    const float* fbb  = (const float*)d_in[7];
    const float* d1w  = (const float*)d_in[8];
    const float* d1b  = (const float*)d_in[9];
    const float* d2w  = (const float*)d_in[10];
    const float* d2b  = (const float*)d_in[11];
    const float* aiw  = (const float*)d_in[12];
    const float* aib  = (const float*)d_in[13];
    const float* aow  = (const float*)d_in[14];
    const float* aob  = (const float*)d_in[15];
    const float* ow   = (const float*)d_in[16];
    const float* ob   = (const float*)d_in[17];
    float* out = (float*)d_out;

    // ws layout: wet 256KB | fbA 256KB (reused as o) | fbB 256KB (reused as blur) | cnt 640B
    float* ws_wet  = (float*)d_ws;
    float* fbA     = ws_wet + 65536;
    float* fbB     = fbA + 65536;
    unsigned* cnt  = (unsigned*)(fbB + 65536);
    float* o_buf    = fbA;      // dead after reverb
    float* blur_buf = fbB;      // dead after reverb

    fused_kernel<<<GRID, 512, 0, stream>>>(
        x, rw, dl, fbw, fbb, d1w, d1b, d2w, d2b,
        aiw, aib, aow, aob, sw, sb, ow, ob,
        (float4*)fbA, (float4*)fbB, (float4*)ws_wet, o_buf, blur_buf, cnt, out);
}

// Round 10
// 288.008 us; speedup vs baseline: 1.5089x; 1.5089x over previous
//
#include <hip/hip_runtime.h>

#define LOG2E 1.4426950408889634f
#define GRID 256
#define RVB 64            // reverb blocks (16 per batch, 4 rows each)
#define MAGIC 0x13579BDFu

// fast sigmoid: rcp approx ~1e-6 rel; tolerance headroom is ~250x
__device__ __forceinline__ float fsig(float z) {
    return __builtin_amdgcn_rcpf(1.0f + exp2f(-z * LOG2E));
}

// ---------------------------------------------------------------------------
// Barriers v4: round-8 memory semantics (threadfence + RELAXED atomics — no
// scoped-acquire L2 flushing), hierarchical arrival (8-block groups -> root)
// to kill the ~90ns-per-RMW single-line serialization seen at 256 arrivals.
// cnt layout (one-shot words, 64B-line spacing where contended):
//   [0] boot flag
//   [64+g*16+slot]  g<8,  slot<16 : reverb group-arrive
//   [192+slot]      slot<16       : reverb root
//   [224+g*16+slot] g<8,  slot<16 : reverb release
//   [352+s]         s<2           : grid root
//   [384+g*16+s]    g<32, s<2     : grid group-arrive
//   [896+g*16+s]    g<32, s<2     : grid release
// ---------------------------------------------------------------------------
__device__ __forceinline__ void rev_bar(unsigned* cnt, int slot) {
    __syncthreads();
    if (threadIdx.x == 0) {
        __threadfence();
        const int g = blockIdx.x >> 3;          // 0..7
        unsigned old = atomicAdd(&cnt[64 + g * 16 + slot], 1u);
        if (old == 7u) {
            unsigned r = atomicAdd(&cnt[192 + slot], 1u);
            if (r == 7u) {
                #pragma unroll
                for (int gg = 0; gg < 8; ++gg)
                    atomicExch(&cnt[224 + gg * 16 + slot], MAGIC);
            }
        }
        unsigned* rel = &cnt[224 + g * 16 + slot];
        while (__hip_atomic_load(rel, __ATOMIC_RELAXED, __HIP_MEMORY_SCOPE_AGENT) != MAGIC)
            __builtin_amdgcn_s_sleep(1);
        __threadfence();
    }
    __syncthreads();
}

template <int SLP>
__device__ __forceinline__ void big_bar(unsigned* cnt, int s) {   // s = 0 or 1
    __syncthreads();
    if (threadIdx.x == 0) {
        __threadfence();
        const int g = blockIdx.x >> 3;          // 0..31
        unsigned old = atomicAdd(&cnt[384 + g * 16 + s], 1u);
        if (old == 7u) {
            unsigned r = atomicAdd(&cnt[352 + s], 1u);
            if (r == 31u) {
                for (int gg = 0; gg < 32; ++gg)
                    atomicExch(&cnt[896 + gg * 16 + s], MAGIC);
            }
        }
        unsigned* rel = &cnt[896 + g * 16 + s];
        while (__hip_atomic_load(rel, __ATOMIC_RELAXED, __HIP_MEMORY_SCOPE_AGENT) != MAGIC)
            __builtin_amdgcn_s_sleep(SLP);
        __threadfence();
    }
    __syncthreads();
}

// ---------------------------------------------------------------------------
// conv3x3(roll(fb)*fade) + damping MLP at one pixel, fb in global (L2).
// ---------------------------------------------------------------------------
__device__ __forceinline__ void conv_damp(
    const float4* __restrict__ src, int yq, int xq, int ys, int xs,
    const float* fe, const float4 wr[9][4],
    const float4 d1w0, const float4 d1w1, const float2 d1b, const float4 d2p[4],
    float rv[4])
{
    float r[4] = { d2p[0].w, d2p[1].w, d2p[2].w, d2p[3].w };   // conv bias (fbb)
    #pragma unroll
    for (int a = 0; a < 3; ++a) {
        int yy = yq - 1 + a;
        float fy = fe[yy + 1];                       // 0 outside image -> zero pad
        const float4* rowp = src + (((yy - ys) & 63) << 6);
        #pragma unroll
        for (int qq = 0; qq < 3; ++qq) {
            int xt = xq - 1 + qq;
            float f = fy * fe[xt + 1];
            float4 v = rowp[(xt - xs) & 63];
            float s0 = v.x * f, s1 = v.y * f, s2 = v.z * f, s3 = v.w * f;
            #pragma unroll
            for (int co = 0; co < 4; ++co) {
                float4 w = wr[a * 3 + qq][co];
                r[co] = fmaf(w.x, s0, fmaf(w.y, s1, fmaf(w.z, s2, fmaf(w.w, s3, r[co]))));
            }
        }
    }
    float z0 = fmaf(d1w0.x, r[0], fmaf(d1w0.y, r[1], fmaf(d1w0.z, r[2], fmaf(d1w0.w, r[3], d1b.x))));
    float z1 = fmaf(d1w1.x, r[0], fmaf(d1w1.y, r[1], fmaf(d1w1.z, r[2], fmaf(d1w1.w, r[3], d1b.y))));
    float h0 = z0 * fsig(z0);
    float h1 = z1 * fsig(z1);
    #pragma unroll
    for (int c = 0; c < 4; ++c) {
        float dm = fsig(fmaf(d2p[c].x, h0, fmaf(d2p[c].y, h1, d2p[c].z)));
        rv[c] = r[c] * dm;
    }
}

// ---------------------------------------------------------------------------
// Single fused kernel: reverb (blocks 0..63, local/remote conv split across
// thread halves) -> attention -> fused proj+blur+edge+final. 2 grid barriers.
// ---------------------------------------------------------------------------
__global__ __launch_bounds__(512) void fused_kernel(
    const float* __restrict__ x, const float* __restrict__ rw, const float* __restrict__ dl,
    const float* __restrict__ fbw, const float* __restrict__ fbb,
    const float* __restrict__ d1wg, const float* __restrict__ d1bg,
    const float* __restrict__ d2wg, const float* __restrict__ d2bg,
    const float* __restrict__ aiw, const float* __restrict__ aib,
    const float* __restrict__ aow, const float* __restrict__ aob,
    const float* __restrict__ swg, const float* __restrict__ sbg,
    const float* __restrict__ owg, const float* __restrict__ obg,
    float4* __restrict__ fbA, float4* __restrict__ fbB,
    float4* __restrict__ ws_wet, float* __restrict__ o_buf,
    unsigned* __restrict__ cnt, float* __restrict__ out)
{
    __shared__ float4 kvs4[2048];     // 32 KB: (k,v) pairs for 4096 keys
    __shared__ float2 part[2048];     // 16 KB
    __shared__ float4 prevL[256];     // 4 KB: remote-half -> local-half handoff
    __shared__ float fe[66];
    __shared__ float4 wvsL[36];
    __shared__ float s_rw[16], s_dl[16];
    __shared__ float4 s_mlp[7];
    __shared__ float s_sw[288], s_ow[48], s_sb[8], s_ob[4];
    __shared__ float redmx[8], redmn[8];

    const int tid = threadIdx.x;
    const int blk = blockIdx.x;

    // ---- stage LDS statics (all blocks) ----
    if (tid < 66) {
        float f = 0.0f;
        if (tid >= 1 && tid <= 64) {
            int j = tid - 1;
            f = 1.0f;
            if (j < 4) f = 0.6f + (0.4f / 3.0f) * j;
            else if (j >= 60) f = 0.6f + (0.4f / 3.0f) * (63 - j);
        }
        fe[tid] = f;
    }
    if (tid >= 128 && tid < 164) {
        int t2 = tid - 128, n = t2 >> 2, co = t2 & 3;
        wvsL[t2] = make_float4(fbw[(co * 4 + 0) * 9 + n], fbw[(co * 4 + 1) * 9 + n],
                               fbw[(co * 4 + 2) * 9 + n], fbw[(co * 4 + 3) * 9 + n]);
    }
    if (tid >= 192 && tid < 208) s_rw[tid - 192] = rw[tid - 192];
    if (tid >= 224 && tid < 240) s_dl[tid - 224] = dl[tid - 224];
    if (tid == 256) {
        s_mlp[0] = make_float4(d1wg[0], d1wg[1], d1wg[2], d1wg[3]);
        s_mlp[1] = make_float4(d1wg[4], d1wg[5], d1wg[6], d1wg[7]);
        s_mlp[2] = make_float4(d1bg[0], d1bg[1], 0.0f, 0.0f);
        for (int c = 0; c < 4; ++c)
            s_mlp[3 + c] = make_float4(d2wg[c * 2], d2wg[c * 2 + 1], d2bg[c], fbb[c]);
    }
    if (tid >= 336 && tid < 384) s_ow[tid - 336] = owg[tid - 336];
    if (tid >= 384 && tid < 392) s_sb[tid - 384] = sbg[tid - 384];
    if (tid >= 392 && tid < 396) s_ob[tid - 392] = obg[tid - 392];
    for (int j = tid; j < 288; j += 512) s_sw[j] = swg[j];

    // ---- boot: block 0 zeros all barrier words, raises flag ----
    if (blk == 0) {
        for (int i = 16 + tid; i < 1408; i += 512) cnt[i] = 0u;
        __syncthreads();
        if (tid == 0) { __threadfence(); atomicExch(&cnt[0], MAGIC); }
    } else {
        __syncthreads();
        if (tid == 0) {
            while (__hip_atomic_load(&cnt[0], __ATOMIC_RELAXED, __HIP_MEMORY_SCOPE_AGENT) != MAGIC)
                __builtin_amdgcn_s_sleep(2);
        }
        __syncthreads();
    }

    // =====================================================================
    // Stage 1: reverb, blocks 0..63. Block = (batch, 4-row slab), 256 px.
    // Threads 0..255: local conv + state; 256..511: remote recompute conv.
    // =====================================================================
    if (blk < RVB) {
        const int half = tid >> 8;
        const int lane = tid & 255;
        const int b    = blk >> 4;
        const int y0   = ((blk & 15) << 2) + (lane >> 6);
        const int xx   = lane & 63;
        const int s_   = (y0 << 6) + xx;
        float4* A = fbA + (b << 12);
        float4* B = fbB + (b << 12);

        float4 wr[9][4];
        #pragma unroll
        for (int n = 0; n < 9; ++n)
            #pragma unroll
            for (int co = 0; co < 4; ++co) wr[n][co] = wvsL[n * 4 + co];
        const float4 d1w0 = s_mlp[0], d1w1 = s_mlp[1];
        const float2 d1b = make_float2(s_mlp[2].x, s_mlp[2].y);
        float4 d2p[4] = { s_mlp[3], s_mlp[4], s_mlp[5], s_mlp[6] };

        float4 fbv;
        float acc0 = 0.0f, acc1 = 0.0f, acc2 = 0.0f, acc3 = 0.0f;
        if (half == 0) {
            fbv.x = 0.1f * x[((b * 4 + 0) << 12) + s_];
            fbv.y = 0.1f * x[((b * 4 + 1) << 12) + s_];
            fbv.z = 0.1f * x[((b * 4 + 2) << 12) + s_];
            fbv.w = 0.1f * x[((b * 4 + 3) << 12) + s_];
            A[s_] = fbv;
        }
        rev_bar(cnt, 0);

        float decay = 1.0f;
        for (int i = 0; i < 16; ++i) {
            const float4* src = (i & 1) ? B : A;
            float4* dst = (i & 1) ? A : B;
            float d = s_dl[i];
            int ys  = ((int)(3.0f * d)) & 63;
            int xs  = ((int)(6.0f * d)) & 63;
            int ys2 = ((int)(1.5f * d)) & 63;
            int xs2 = ((int)(3.0f * d)) & 63;

            float4 fnew;
            if (half == 0) {
                float wgt = fsig(s_rw[i]) * decay * 3.0f;
                float rv[4];
                conv_damp(src, y0, xx, ys, xs, fe, wr, d1w0, d1w1, d1b, d2p, rv);
                acc0 = fmaf(rv[0], wgt, acc0);
                acc1 = fmaf(rv[1], wgt, acc1);
                acc2 = fmaf(rv[2], wgt, acc2);
                acc3 = fmaf(rv[3], wgt, acc3);
                fnew = make_float4(fbv.x + 0.24f * rv[0], fbv.y + 0.24f * rv[1],
                                   fbv.z + 0.24f * rv[2], fbv.w + 0.24f * rv[3]);
            } else if (i > 0) {
                // prev = roll(fbI, d/2)*fades; fbI at remote px recomputed here
                int yr = (y0 - ys2) & 63, xr = (xx - xs2) & 63;
                float rvr[4];
                conv_damp(src, yr, xr, ys, xs, fe, wr, d1w0, d1w1, d1b, d2p, rvr);
                float4 fr = src[(yr << 6) + xr];
                float f = 0.08f * fe[y0 + 1] * fe[xx + 1];
                prevL[lane] = make_float4(f * fmaf(0.24f, rvr[0], fr.x),
                                          f * fmaf(0.24f, rvr[1], fr.y),
                                          f * fmaf(0.24f, rvr[2], fr.z),
                                          f * fmaf(0.24f, rvr[3], fr.w));
            }
            __syncthreads();
            if (half == 0) {
                if (i > 0) {
                    float4 pa = prevL[lane];
                    fnew.x += pa.x; fnew.y += pa.y; fnew.z += pa.z; fnew.w += pa.w;
                }
                dst[s_] = fnew;
                fbv = fnew;
            }
            decay *= 0.8f;
            if (i < 15) rev_bar(cnt, 1 + i);
        }
        if (half == 0) ws_wet[(b << 12) + s_] = make_float4(acc0, acc1, acc2, acc3);
        big_bar<1>(cnt, 0);
    } else {
        big_bar<8>(cnt, 0);    // idle during reverb: coarse sleep on own group line
    }

    // =====================================================================
    // Stage 2: attention (head_dim=1). Block = (b,h, 256-row chunk).
    // 512 thr = 64 row-slots (4 rows each) x 8 key-groups (512 keys each).
    // =====================================================================
    {
        const int bh = blk >> 4;
        const int ab = bh >> 2, ah = bh & 3;
        const int qc = blk & 15;

        float wq[4], wk[4], wv[4];
        #pragma unroll
        for (int c = 0; c < 4; ++c) {
            wq[c] = aiw[ah * 4 + c];
            wk[c] = aiw[(4 + ah) * 4 + c];
            wv[c] = aiw[(8 + ah) * 4 + c];
        }
        const float bq = aib[ah], bk = aib[4 + ah], bv = aib[8 + ah];

        float2* kvs = (float2*)kvs4;
        float lmax = -1e30f, lmin = 1e30f;
        for (int s = tid; s < 4096; s += 512) {
            float4 w4 = ws_wet[(ab << 12) + s];
            float k = wk[0] * w4.x + wk[1] * w4.y + wk[2] * w4.z + wk[3] * w4.w + bk;
            float v = wv[0] * w4.x + wv[1] * w4.y + wv[2] * w4.z + wv[3] * w4.w + bv;
            kvs[s] = make_float2(k, v);
            lmax = fmaxf(lmax, k); lmin = fminf(lmin, k);
        }
        #pragma unroll
        for (int off = 32; off > 0; off >>= 1) {
            lmax = fmaxf(lmax, __shfl_xor(lmax, off));
            lmin = fminf(lmin, __shfl_xor(lmin, off));
        }
        if ((tid & 63) == 0) { redmx[tid >> 6] = lmax; redmn[tid >> 6] = lmin; }
        __syncthreads();
        float kmax = redmx[0], kmin = redmn[0];
        #pragma unroll
        for (int w = 1; w < 8; ++w) { kmax = fmaxf(kmax, redmx[w]); kmin = fminf(kmin, redmn[w]); }

        const int rs = tid & 63;
        const int kg = tid >> 6;
        float qL[4], mL[4];
        #pragma unroll
        for (int rr = 0; rr < 4; ++rr) {
            int row = (qc << 8) + (rs << 2) + rr;
            float4 w4 = ws_wet[(ab << 12) + row];
            float q = wq[0] * w4.x + wq[1] * w4.y + wq[2] * w4.z + wq[3] * w4.w + bq;
            float m = (q >= 0.0f) ? q * kmax : q * kmin;   // exact row max (hd=1)
            qL[rr] = q * LOG2E; mL[rr] = m * LOG2E;
        }

        float den[4] = {0, 0, 0, 0}, num[4] = {0, 0, 0, 0};
        const int j0 = kg << 8;        // 256 float4 = 512 keys per group
        #pragma unroll 2
        for (int j = j0; j < j0 + 256; ++j) {
            float4 t = kvs4[j];
            #pragma unroll
            for (int rr = 0; rr < 4; ++rr) {
                float e0 = exp2f(fmaf(qL[rr], t.x, -mL[rr]));
                float e1 = exp2f(fmaf(qL[rr], t.z, -mL[rr]));
                den[rr] += e0 + e1;
                num[rr] = fmaf(e0, t.y, fmaf(e1, t.w, num[rr]));
            }
        }
        #pragma unroll
        for (int rr = 0; rr < 4; ++rr)
            part[(kg << 8) + (rs << 2) + rr] = make_float2(den[rr], num[rr]);
        __syncthreads();
        if (tid < 256) {
            float dd = 0.0f, nn = 0.0f;
            #pragma unroll
            for (int g = 0; g < 8; ++g) {
                float2 pp = part[(g << 8) + tid];
                dd += pp.x; nn += pp.y;
            }
            int row = (qc << 8) + tid;
            o_buf[(((ab << 12) + row) << 2) + ah] = nn * __builtin_amdgcn_rcpf(dd);
        }
    }
    big_bar<2>(cnt, 1);

    // =====================================================================
    // Stage 3 (fused proj+blur+edge + spatial conv + combine + mix).
    // proj is linear -> blur(pos) = (W . S(pos) + n_valid*b)/9 where S is the
    // 3x3 window-sum of o vectors. Block owns 64 px; thread = (px, cout).
    // =====================================================================
    if (tid < 256) {
        const int co = tid >> 6;
        const int pl = (blk << 6) + (tid & 63);
        const int fb_ = pl >> 12, ss = pl & 4095;
        const int y = ss >> 6, x0 = ss & 63;
        const float4* o4p = (const float4*)o_buf + (fb_ << 12);

        // spatial_features = conv3x3(x) (8 ch)
        float spat[8];
        #pragma unroll
        for (int j = 0; j < 8; ++j) spat[j] = s_sb[j];
        for (int dy = -1; dy <= 1; ++dy) {
            int yy = y + dy;
            if (yy < 0 || yy > 63) continue;
            for (int dx = -1; dx <= 1; ++dx) {
                int xc = x0 + dx;
                if (xc < 0 || xc > 63) continue;
                int ky = dy + 1, kx = dx + 1;
                #pragma unroll
                for (int ci = 0; ci < 4; ++ci) {
                    float xv = x[((fb_ * 4 + ci) << 12) + (yy << 6) + xc];
                    #pragma unroll
                    for (int j = 0; j < 8; ++j)
                        spat[j] += s_sw[((j * 4 + ci) * 3 + ky) * 3 + kx] * xv;
                }
            }
        }

        // 3x3 window-sums of o over the 5x5 neighborhood (zero OOB)
        float4 colS[5][3];
        #pragma unroll
        for (int j = 0; j < 5; ++j) {
            int xc = x0 - 2 + j;
            bool cok = (xc >= 0 && xc <= 63);
            float4 o[5];
            #pragma unroll
            for (int r = 0; r < 5; ++r) {
                int yy = y - 2 + r;
                if (cok && yy >= 0 && yy <= 63) o[r] = o4p[(yy << 6) + xc];
                else o[r] = make_float4(0.f, 0.f, 0.f, 0.f);
            }
            #pragma unroll
            for (int k = 0; k < 3; ++k)
                colS[j][k] = make_float4(o[k].x + o[k+1].x + o[k+2].x,
                                         o[k].y + o[k+1].y + o[k+2].y,
                                         o[k].z + o[k+1].z + o[k+2].z,
                                         o[k].w + o[k+1].w + o[k+2].w);
        }
        float4 S[3][3];
        float vr[3], vc[3];
        #pragma unroll
        for (int k = 0; k < 3; ++k) {
            int cr = 0, cc = 0;
            #pragma unroll
            for (int d = -1; d <= 1; ++d) {
                int yy = y + (k - 1) + d; if (yy >= 0 && yy <= 63) ++cr;
                int xc = x0 + (k - 1) + d; if (xc >= 0 && xc <= 63) ++cc;
            }
            vr[k] = (float)cr; vc[k] = (float)cc;
        }
        #pragma unroll
        for (int wy = 0; wy < 3; ++wy)
            #pragma unroll
            for (int wx = 0; wx < 3; ++wx)
                S[wy][wx] = make_float4(
                    colS[wx][wy].x + colS[wx+1][wy].x + colS[wx+2][wy].x,
                    colS[wx][wy].y + colS[wx+1][wy].y + colS[wx+2][wy].y,
                    colS[wx][wy].z + colS[wx+1][wy].z + colS[wx+2][wy].z,
                    colS[wx][wy].w + colS[wx+1][wy].w + colS[wx+2][wy].w);

        float wetF[4];
        #pragma unroll
        for (int c = 0; c < 4; ++c) {
            float w0 = aow[c*4], w1 = aow[c*4+1], w2 = aow[c*4+2], w3 = aow[c*4+3];
            float bc = aob[c];
            float center = 0.0f, sum9 = 0.0f;
            #pragma unroll
            for (int wy = 0; wy < 3; ++wy) {
                int yy = y + wy - 1;
                #pragma unroll
                for (int wx = 0; wx < 3; ++wx) {
                    int xc = x0 + wx - 1;
                    float bl = (w0*S[wy][wx].x + w1*S[wy][wx].y + w2*S[wy][wx].z
                              + w3*S[wy][wx].w + vr[wy]*vc[wx]*bc) * (1.0f/9.0f);
                    if (wy == 1 && wx == 1) center = bl;
                    if (yy >= 0 && yy <= 63 && xc >= 0 && xc <= 63) sum9 += bl;
                }
            }
            wetF[c] = center + 0.04f * (9.0f * center - sum9);
        }

        float pv = s_ob[co];
        #pragma unroll
        for (int j = 0; j < 8; ++j) pv += s_ow[co * 12 + j] * spat[j];
        #pragma unroll
        for (int c = 0; c < 4; ++c) pv += s_ow[co * 12 + 8 + c] * wetF[c];
        float xc0 = x[((fb_ * 4 + co) << 12) + ss];
        out[((fb_ * 4 + co) << 12) + ss] = 0.7f * xc0 + 0.3f * pv;
    }
}

// ---------------------------------------------------------------------------
extern "C" void kernel_launch(void* const* d_in, const int* in_sizes, int n_in,
                              void* d_out, int out_size, void* d_ws, size_t ws_size,
                              hipStream_t stream)
{
    (void)in_sizes; (void)n_in; (void)out_size; (void)ws_size;
    const float* x    = (const float*)d_in[0];
    const float* rw   = (const float*)d_in[1];
    const float* dl   = (const float*)d_in[2];
    // d_in[3] diffusion_strength: unused by reference
    const float* sw   = (const float*)d_in[4];
    const float* sb   = (const float*)d_in[5];
    const float* fbw  = (const float*)d_in[6];
    const float* fbb  = (const float*)d_in[7];
    const float* d1w  = (const float*)d_in[8];
    const float* d1b  = (const float*)d_in[9];
    const float* d2w  = (const float*)d_in[10];
    const float* d2b  = (const float*)d_in[11];
    const float* aiw  = (const float*)d_in[12];
    const float* aib  = (const float*)d_in[13];
    const float* aow  = (const float*)d_in[14];
    const float* aob  = (const float*)d_in[15];
    const float* ow   = (const float*)d_in[16];
    const float* ob   = (const float*)d_in[17];
    float* out = (float*)d_out;

    // ws layout: wet 256KB | fbA 256KB (reused as o_buf) | fbB 256KB | cnt 5.5KB
    float* ws_wet  = (float*)d_ws;
    float* fbA     = ws_wet + 65536;
    float* fbB     = fbA + 65536;
    unsigned* cnt  = (unsigned*)(fbB + 65536);
    float* o_buf   = fbA;      // dead after reverb

    fused_kernel<<<GRID, 512, 0, stream>>>(
        x, rw, dl, fbw, fbb, d1w, d1b, d2w, d2b,
        aiw, aib, aow, aob, sw, sb, ow, ob,
        (float4*)fbA, (float4*)fbB, (float4*)ws_wet, o_buf, cnt, out);
}